// Round 6
// baseline (326.201 us; speedup 1.0000x reference)
//
#include <hip/hip_runtime.h>
#include <math.h>

#define F_IN 12
#define NHID 64
#define HGCN 61
#define EMB_OUT 54
#define SCAN_CH 1024
#define PART_R 8192           // edge records per partition block (LDS-staged)
#define PART_M 8192           // mask records per partition block / edges per window
#define DEG_SCALE 32768.0f    // 2^15 fixed-point for weighted degree

typedef unsigned int uint;
typedef unsigned short ushort;
typedef unsigned char uchar;

__device__ __forceinline__ float gelu_exact(float v) {
    return 0.5f * v * (1.0f + erff(v * 0.70710678118654752440f));
}

__device__ __forceinline__ void atomic_add_f32(float* p, float v) {
    unsafeAtomicAdd(p, v);   // hardware global_atomic_add_f32
}

// ---- prep: weight table sp[4] = {1.0 (no mask), softmax0, softmax1, softmax2};
//      spq fixed-point; fold W_emb/b_emb into W_gcn -> W_eff(12x64), b_eff
__global__ void prep_kernel(const float* __restrict__ msg_w,
                            const float* __restrict__ W_emb,
                            const float* __restrict__ b_emb,
                            const float* __restrict__ W_gcn,
                            float* __restrict__ sp, uint* __restrict__ spq,
                            float* __restrict__ W_eff, float* __restrict__ b_eff) {
    __shared__ float ssp[4];
    int t = threadIdx.x;
    if (t == 0) {
        float m = fmaxf(msg_w[0], fmaxf(msg_w[1], msg_w[2]));
        float e0 = expf(msg_w[0] - m), e1 = expf(msg_w[1] - m), e2 = expf(msg_w[2] - m);
        float s = e0 + e1 + e2;
        ssp[0] = 1.0f; ssp[1] = e0 / s; ssp[2] = e1 / s; ssp[3] = e2 / s;
        sp[0] = ssp[0]; sp[1] = ssp[1]; sp[2] = ssp[2]; sp[3] = ssp[3];
    }
    __syncthreads();
    if (t < 4) spq[t] = __float2uint_rn(ssp[t] * DEG_SCALE);
    if (t < HGCN) {
        float be = 0.f, w0 = 0.f, w1 = 0.f;
        for (int k = 0; k < EMB_OUT; ++k) {
            float g = W_gcn[k * HGCN + t];
            be += b_emb[k] * g;
            w0 += W_emb[k] * g;
            w1 += W_emb[EMB_OUT + k] * g;
        }
        b_eff[t] = be;
        W_eff[0 * 64 + t] = w0;
        W_eff[1 * 64 + t] = w1;
        for (int f = 2; f < F_IN; ++f)
            W_eff[f * 64 + t] = W_gcn[(EMB_OUT + f - 2) * HGCN + t];
    }
}

// ---- mask pipeline: concatenated (known,unk,obs) stream, code 1/2/3 by position.
// Priority "later kernel wins" == numeric max of codes (none=0).
__device__ __forceinline__ int mask_val(const int* kn, const int* uk, const int* ob,
                                        int nk, int nu, int i) {
    return (i < nk) ? kn[i] : (i < nk + nu) ? uk[i - nk] : ob[i - nk - nu];
}

// M1: per-block histogram of edge-windows (e>>13) -> H2[w*NMB + blk]
__global__ __launch_bounds__(256) void m1_hist(const int* __restrict__ kn,
                                               const int* __restrict__ uk,
                                               const int* __restrict__ ob,
                                               int nk, int nu, int M,
                                               uint* __restrict__ H2, int NW, int NMB) {
    __shared__ uint hist[512];
    int blk = blockIdx.x, t = threadIdx.x;
    hist[t] = 0; hist[t + 256] = 0;
    __syncthreads();
    int lo = blk * PART_M, hi = min(lo + PART_M, M);
    for (int i = lo + t; i < hi; i += 256)
        atomicAdd(&hist[((uint)mask_val(kn, uk, ob, nk, nu, i)) >> 13], 1u);
    __syncthreads();
    for (int w = t; w < NW; w += 256) H2[(size_t)w * NMB + blk] = hist[w];
}

// M3: LDS-staged partition of mask records (u16 = (e&8191)<<2 | code) into windows
__global__ __launch_bounds__(256) void m3_partition(
        const int* __restrict__ kn, const int* __restrict__ uk, const int* __restrict__ ob,
        int nk, int nu, int M, const uint* __restrict__ Hs2,
        ushort* __restrict__ recM, int NW, int NMB) {
    __shared__ ushort recs[PART_M];
    __shared__ ushort sbkt[PART_M];
    __shared__ uint hist[512], scanA[512], scanB[512], cursor[512];
    __shared__ int gbase[512];
    int blk = blockIdx.x, t = threadIdx.x;
    int lo = blk * PART_M, hi = min(lo + PART_M, M);
    int cntTot = hi - lo;
    hist[t] = 0; hist[t + 256] = 0;
    __syncthreads();
    for (int i = lo + t; i < hi; i += 256)
        atomicAdd(&hist[((uint)mask_val(kn, uk, ob, nk, nu, i)) >> 13], 1u);
    __syncthreads();
    uint* src = scanA; uint* dst = scanB;
    src[t] = hist[t]; src[t + 256] = hist[t + 256];
    __syncthreads();
    for (int off = 1; off < 512; off <<= 1) {
        dst[t]       = src[t]       + ((t >= off)       ? src[t - off]       : 0u);
        dst[t + 256] = src[t + 256] + ((t + 256 >= off) ? src[t + 256 - off] : 0u);
        __syncthreads();
        uint* tmp = src; src = dst; dst = tmp;
    }
    uint l0 = (t == 0) ? 0u : src[t - 1];
    uint l1 = src[t + 255];
    cursor[t] = l0; cursor[t + 256] = l1;
    if (t < NW)       gbase[t]       = (int)Hs2[(size_t)t * NMB + blk]         - (int)l0;
    if (t + 256 < NW) gbase[t + 256] = (int)Hs2[(size_t)(t + 256) * NMB + blk] - (int)l1;
    __syncthreads();
    for (int i = lo + t; i < hi; i += 256) {
        int e; uint code;
        if (i < nk)           { e = kn[i];           code = 1u; }
        else if (i < nk + nu) { e = uk[i - nk];      code = 2u; }
        else                  { e = ob[i - nk - nu]; code = 3u; }
        uint w = ((uint)e) >> 13;
        ushort rec = (ushort)((((uint)e & 8191u) << 2) | code);
        uint slot = atomicAdd(&cursor[w], 1u);
        recs[slot] = rec;
        sbkt[slot] = (ushort)w;
    }
    __syncthreads();
    for (int s = t; s < cntTot; s += 256)
        recM[gbase[sbkt[s]] + s] = recs[s];
}

// M4: one block per window: apply codes in 3 priority phases into LDS, write wclass coalesced
__global__ __launch_bounds__(256) void m4_apply(const ushort* __restrict__ recM,
                                                const uint* __restrict__ Hs2,
                                                uchar* __restrict__ wclass,
                                                int E, int M, int NW, int NMB) {
    __shared__ uchar cls[PART_M];
    int w = blockIdx.x, t = threadIdx.x;
    for (int i = t; i < PART_M; i += 256) cls[i] = 0;
    __syncthreads();
    uint lo = Hs2[(size_t)w * NMB];
    uint hi = (w + 1 < NW) ? Hs2[(size_t)(w + 1) * NMB] : (uint)M;
#pragma unroll
    for (uint c = 1; c <= 3; ++c) {
        for (uint i = lo + t; i < hi; i += 256) {
            uint r = recM[i];
            if ((r & 3u) == c) cls[r >> 2] = (uchar)c;
        }
        __syncthreads();
    }
    int base = w << 13;
    int n = min(PART_M, E - base);
    for (int i = t; i < n; i += 256) wclass[base + i] = cls[i];
}

// K1: per-block histogram of destination buckets (col>>8) -> H[bucket*NBLK + blk]
__global__ __launch_bounds__(256) void k1_hist(const int* __restrict__ ei,
                                               uint* __restrict__ H,
                                               int E, int NB, int NBLK) {
    __shared__ uint hist[512];
    int blk = blockIdx.x, t = threadIdx.x;
    hist[t] = 0; hist[t + 256] = 0;
    __syncthreads();
    int lo = blk * PART_R, hi = min(lo + PART_R, E);
    for (int i = lo + t; i < hi; i += 256)
        atomicAdd(&hist[((uint)ei[E + i]) >> 8], 1u);
    __syncthreads();
    for (int b = t; b < NB; b += 256) H[(size_t)b * NBLK + blk] = hist[b];
}

// ---- exclusive scan (3 kernels, generic length)
__global__ void scan_partial_kernel(const int* __restrict__ cnt, int* __restrict__ startv,
                                    int* __restrict__ bsum, int n) {
    __shared__ int s[256];
    int t = threadIdx.x;
    int base = blockIdx.x * SCAN_CH + t * 4;
    int v0 = (base + 0 < n) ? cnt[base + 0] : 0;
    int v1 = (base + 1 < n) ? cnt[base + 1] : 0;
    int v2 = (base + 2 < n) ? cnt[base + 2] : 0;
    int v3 = (base + 3 < n) ? cnt[base + 3] : 0;
    int loc = v0 + v1 + v2 + v3;
    s[t] = loc;
    __syncthreads();
    for (int off = 1; off < 256; off <<= 1) {
        int u = (t >= off) ? s[t - off] : 0;
        __syncthreads();
        s[t] += u;
        __syncthreads();
    }
    int ex = s[t] - loc;
    if (t == 255) bsum[blockIdx.x] = s[255];
    if (base + 0 < n) startv[base + 0] = ex;
    if (base + 1 < n) startv[base + 1] = ex + v0;
    if (base + 2 < n) startv[base + 2] = ex + v0 + v1;
    if (base + 3 < n) startv[base + 3] = ex + v0 + v1 + v2;
}

__global__ void scan_bsum_kernel(int* __restrict__ bsum, int nb) {
    if (threadIdx.x == 0 && blockIdx.x == 0) {
        int acc = 0;
        for (int i = 0; i < nb; ++i) { int v = bsum[i]; bsum[i] = acc; acc += v; }
    }
}

__global__ void scan_add_kernel(int* __restrict__ startv, const int* __restrict__ bsum, int n) {
    int i = blockIdx.x * blockDim.x + threadIdx.x;
    if (i < n) startv[i] += bsum[i / SCAN_CH];
}

// K3: LDS-staged partition to BUCKET granularity.
// Pack rec = row<<10 | (col&255)<<2 | wclass; write bucket-grouped.
__global__ __launch_bounds__(256) void k3_partition(
        const int* __restrict__ ei, const uchar* __restrict__ wclass,
        const uint* __restrict__ Hs, uint* __restrict__ recSorted,
        int E, int NB, int NBLK) {
    __shared__ uint recs[PART_R];
    __shared__ ushort sbkt[PART_R];
    __shared__ uint hist[512];
    __shared__ uint scanA[512];
    __shared__ uint scanB[512];
    __shared__ int  gbase[512];
    __shared__ uint cursor[512];
    int blk = blockIdx.x, t = threadIdx.x;
    int lo = blk * PART_R, hi = min(lo + PART_R, E);
    int cntTot = hi - lo;
    hist[t] = 0; hist[t + 256] = 0;
    __syncthreads();
    for (int i = lo + t; i < hi; i += 256)
        atomicAdd(&hist[((uint)ei[E + i]) >> 8], 1u);
    __syncthreads();
    uint* src = scanA; uint* dst = scanB;
    src[t] = hist[t]; src[t + 256] = hist[t + 256];
    __syncthreads();
    for (int off = 1; off < 512; off <<= 1) {
        dst[t]       = src[t]       + ((t >= off)       ? src[t - off]       : 0u);
        dst[t + 256] = src[t + 256] + ((t + 256 >= off) ? src[t + 256 - off] : 0u);
        __syncthreads();
        uint* tmp = src; src = dst; dst = tmp;
    }
    uint l0 = (t == 0) ? 0u : src[t - 1];
    uint l1 = src[t + 255];
    cursor[t] = l0; cursor[t + 256] = l1;
    if (t < NB)       gbase[t]       = (int)Hs[(size_t)t * NBLK + blk]         - (int)l0;
    if (t + 256 < NB) gbase[t + 256] = (int)Hs[(size_t)(t + 256) * NBLK + blk] - (int)l1;
    __syncthreads();
    for (int i = lo + t; i < hi; i += 256) {
        uint row = (uint)ei[i];
        uint col = (uint)ei[E + i];
        uint b = col >> 8;
        uint rec = (row << 10) | ((col & 255u) << 2) | (uint)wclass[i];
        uint slot = atomicAdd(&cursor[b], 1u);
        recs[slot] = rec;
        sbkt[slot] = (ushort)b;
    }
    __syncthreads();
    for (int s = t; s < cntTot; s += 256)
        recSorted[gbase[sbkt[s]] + s] = recs[s];
}

// K2: per-bucket node stats: cnt, startv (node-exact global CSR offset), dis = rsqrt(deg+1)
__global__ __launch_bounds__(256) void k2_stats(
        const uint* __restrict__ recSorted, const uint* __restrict__ Hs,
        const uint* __restrict__ spq,
        uint* __restrict__ cnt, uint* __restrict__ startv, float* __restrict__ dis,
        int E, int NB, int NBLK, int n_nodes) {
    __shared__ uint hcnt[256], hdeg[256], sA[256], sB[256];
    __shared__ uint sq[4];
    int b = blockIdx.x, t = threadIdx.x;
    hcnt[t] = 0; hdeg[t] = 0;
    if (t < 4) sq[t] = spq[t];
    __syncthreads();
    uint lo = Hs[(size_t)b * NBLK];
    uint hi = (b + 1 < NB) ? Hs[(size_t)(b + 1) * NBLK] : (uint)E;
    for (uint i = lo + t; i < hi; i += 256) {
        uint r = recSorted[i];
        atomicAdd(&hcnt[(r >> 2) & 255u], 1u);
        atomicAdd(&hdeg[(r >> 2) & 255u], sq[r & 3u]);
    }
    __syncthreads();
    uint* src = sA; uint* dst = sB;
    src[t] = hcnt[t];
    __syncthreads();
    for (int off = 1; off < 256; off <<= 1) {
        dst[t] = src[t] + ((t >= off) ? src[t - off] : 0u);
        __syncthreads();
        uint* tmp = src; src = dst; dst = tmp;
    }
    uint excl = (t == 0) ? 0u : src[t - 1];
    int node = (b << 8) + t;
    if (node < n_nodes) {
        cnt[node] = hcnt[t];
        startv[node] = lo + excl;
        float deg = (float)hdeg[t] * (1.0f / DEG_SCALE) + 1.0f;
        dis[node] = rsqrtf(deg);
    }
}

// K4: second-level partition + payload fill (writes stay in bucket's L2-resident window)
__global__ __launch_bounds__(256) void k4_payload(
        const uint* __restrict__ recSorted, const uint* __restrict__ Hs,
        const float* __restrict__ sp, const float* __restrict__ dis,
        const uint* __restrict__ startv,
        int2* __restrict__ payload, int E, int NB, int NBLK, int n_nodes) {
    __shared__ float disl[256];
    __shared__ uint cur[256];
    __shared__ float spl[4];
    int b = blockIdx.x, t = threadIdx.x;
    int node = (b << 8) + t;
    disl[t] = (node < n_nodes) ? dis[node] : 0.0f;
    cur[t]  = (node < n_nodes) ? startv[node] : 0u;
    if (t < 4) spl[t] = sp[t];
    __syncthreads();
    uint lo = Hs[(size_t)b * NBLK];
    uint hi = (b + 1 < NB) ? Hs[(size_t)(b + 1) * NBLK] : (uint)E;
    for (uint i = lo + t; i < hi; i += 256) {
        uint r = recSorted[i];
        uint row = r >> 10;
        uint c = (r >> 2) & 255u;
        float nrm = dis[row] * spl[r & 3u] * disl[c];
        uint pos = atomicAdd(&cur[c], 1u);
        payload[pos] = make_int2((int)row, __float_as_int(nrm));
    }
}

// h2 = x @ W_eff + b_eff (stride-64 padded, zeros at d>=61)
__global__ void h2_kernel(const float* __restrict__ x, const float* __restrict__ W_eff,
                          const float* __restrict__ b_eff,
                          float* __restrict__ h2, int n_nodes) {
    int node = blockIdx.x * 4 + (threadIdx.x >> 6);
    int d = threadIdx.x & 63;
    if (node >= n_nodes) return;
    float v = 0.f;
    if (d < HGCN) {
        v = b_eff[d];
#pragma unroll
        for (int f = 0; f < F_IN; ++f)
            v += x[node * F_IN + f] * W_eff[f * 64 + d];
    }
    h2[node * 64 + d] = v;
}

// gather (one wave per destination node) + gelu + pool, fused; 8 loads in flight
__global__ void gather_pool_kernel(const int2* __restrict__ payload,
                                   const uint* __restrict__ startv, const uint* __restrict__ cnt,
                                   const float* __restrict__ dis, const float* __restrict__ h2,
                                   const float* __restrict__ b_gcn, const int* __restrict__ batch,
                                   float* __restrict__ pooled, int n_nodes) {
    int node = blockIdx.x * 4 + (threadIdx.x >> 6);
    int d = threadIdx.x & 63;
    if (node >= n_nodes) return;
    int s = (int)startv[node];
    int m = (int)cnt[node];
    float di = dis[node];
    float acc = di * di * h2[node * 64 + d];      // self-loop term
    for (int j0 = 0; j0 < m; j0 += 64) {
        int2 p = make_int2(0, 0);
        if (j0 + d < m) p = payload[s + j0 + d];  // coalesced 512B load
        int lim = min(64, m - j0);
        int k = 0;
        for (; k + 8 <= lim; k += 8) {            // 8 independent loads in flight
            int r0 = __shfl(p.x, k),     r1 = __shfl(p.x, k + 1);
            int r2 = __shfl(p.x, k + 2), r3 = __shfl(p.x, k + 3);
            int r4 = __shfl(p.x, k + 4), r5 = __shfl(p.x, k + 5);
            int r6 = __shfl(p.x, k + 6), r7 = __shfl(p.x, k + 7);
            float n0 = __int_as_float(__shfl(p.y, k));
            float n1 = __int_as_float(__shfl(p.y, k + 1));
            float n2 = __int_as_float(__shfl(p.y, k + 2));
            float n3 = __int_as_float(__shfl(p.y, k + 3));
            float n4 = __int_as_float(__shfl(p.y, k + 4));
            float n5 = __int_as_float(__shfl(p.y, k + 5));
            float n6 = __int_as_float(__shfl(p.y, k + 6));
            float n7 = __int_as_float(__shfl(p.y, k + 7));
            float h0 = h2[r0 * 64 + d], h1 = h2[r1 * 64 + d];
            float g2 = h2[r2 * 64 + d], h3 = h2[r3 * 64 + d];
            float h4 = h2[r4 * 64 + d], h5 = h2[r5 * 64 + d];
            float h6 = h2[r6 * 64 + d], h7 = h2[r7 * 64 + d];
            acc += n0 * h0; acc += n1 * h1; acc += n2 * g2; acc += n3 * h3;
            acc += n4 * h4; acc += n5 * h5; acc += n6 * h6; acc += n7 * h7;
        }
        for (; k < lim; ++k) {
            int   r = __shfl(p.x, k);
            float nv = __int_as_float(__shfl(p.y, k));
            acc += nv * h2[r * 64 + d];
        }
    }
    if (d < HGCN) {
        float v = gelu_exact(acc + b_gcn[d]);
        atomic_add_f32(&pooled[batch[node] * 64 + d], v);
    }
}

// per-graph head
__global__ void final_kernel(const float* __restrict__ pooled,
                             const float* __restrict__ fn_avg,
                             const float* __restrict__ inf_rate,
                             const float* __restrict__ W_fn1, const float* __restrict__ b_fn1,
                             const float* __restrict__ W_fn2, const float* __restrict__ b_fn2,
                             const float* __restrict__ W_bb1, const float* __restrict__ b_bb1,
                             const float* __restrict__ W_out, const float* __restrict__ b_out,
                             float* __restrict__ logits) {
    __shared__ float z[64];
    __shared__ float t1[16];
    int g = blockIdx.x;
    int t = threadIdx.x;
    if (t < HGCN) z[t] = pooled[g * 64 + t];
    float e0 = fn_avg[g * 2], e1 = fn_avg[g * 2 + 1], e2 = inf_rate[g];
    if (t < 16) {
        float a = e0 * W_fn1[t] + e1 * W_fn1[16 + t] + e2 * W_fn1[32 + t] + b_fn1[t];
        t1[t] = gelu_exact(a);
    }
    __syncthreads();
    if (t < 3) {
        float a = b_fn2[t];
#pragma unroll
        for (int k = 0; k < 16; ++k) a += t1[k] * W_fn2[k * 3 + t];
        z[HGCN + t] = a;
    }
    __syncthreads();
    float acc = b_bb1[t];
#pragma unroll 8
    for (int k = 0; k < 64; ++k) acc += z[k] * W_bb1[k * 64 + t];
    float p = gelu_exact(acc) * W_out[t];
#pragma unroll
    for (int off = 32; off > 0; off >>= 1) p += __shfl_down(p, off);
    if (t == 0) logits[g] = p + b_out[0];
}

extern "C" void kernel_launch(void* const* d_in, const int* in_sizes, int n_in,
                              void* d_out, int out_size, void* d_ws, size_t ws_size,
                              hipStream_t stream) {
    const float* x        = (const float*)d_in[0];
    const int*   ei       = (const int*)d_in[1];
    const int*   batch    = (const int*)d_in[2];
    const int*   known    = (const int*)d_in[3];
    const int*   unk      = (const int*)d_in[4];
    const int*   obs      = (const int*)d_in[5];
    const float* fn_avg   = (const float*)d_in[6];
    const float* inf_rate = (const float*)d_in[7];
    const float* msg_w    = (const float*)d_in[8];
    const float* W_emb    = (const float*)d_in[9];
    const float* b_emb    = (const float*)d_in[10];
    const float* W_gcn    = (const float*)d_in[11];
    const float* b_gcn    = (const float*)d_in[12];
    const float* W_fn1    = (const float*)d_in[13];
    const float* b_fn1    = (const float*)d_in[14];
    const float* W_fn2    = (const float*)d_in[15];
    const float* b_fn2    = (const float*)d_in[16];
    const float* W_bb1    = (const float*)d_in[17];
    const float* b_bb1    = (const float*)d_in[18];
    const float* W_out    = (const float*)d_in[19];
    const float* b_out    = (const float*)d_in[20];
    float* logits = (float*)d_out;

    const int n_nodes = in_sizes[0] / F_IN;
    const int E       = in_sizes[1] / 2;
    const int nk = in_sizes[3], nu = in_sizes[4], no = in_sizes[5];
    const int G = in_sizes[6] / 2;
    const int M = nk + nu + no;

    const int NB   = (n_nodes + 255) >> 8;
    const int NBLK = (E + PART_R - 1) / PART_R;
    const int L    = NB * NBLK;
    const int nbL  = (L + SCAN_CH - 1) / SCAN_CH;

    const int NW   = (E + PART_M - 1) / PART_M;
    const int NMB  = (M + PART_M - 1) / PART_M;
    const int L2   = NW * NMB;
    const int nbL2 = (L2 + SCAN_CH - 1) / SCAN_CH;

    char* ws = (char*)d_ws;
    size_t off = 0;
    auto alloc = [&](size_t bytes) -> void* {
        void* p = ws + off;
        off += (bytes + 255) & ~size_t(255);
        return p;
    };
    uchar*  wclass    = (uchar*)alloc(sizeof(uchar) * (size_t)E);
    uint*   recSorted = (uint*)alloc(sizeof(uint) * (size_t)E);
    ushort* recM      = (ushort*)alloc(sizeof(ushort) * (size_t)M);
    uint*   H         = (uint*)alloc(sizeof(uint) * (size_t)L);
    uint*   Hs        = (uint*)alloc(sizeof(uint) * (size_t)L);
    uint*   H2        = (uint*)alloc(sizeof(uint) * (size_t)L2);
    uint*   Hs2       = (uint*)alloc(sizeof(uint) * (size_t)L2);
    int*    bsum      = (int*)alloc(sizeof(int) * (size_t)(nbL + 1));
    int*    bsum2     = (int*)alloc(sizeof(int) * (size_t)(nbL2 + 1));
    float*  h2        = (float*)alloc(sizeof(float) * (size_t)n_nodes * 64);
    int2*   payload   = (int2*)alloc(sizeof(int2) * (size_t)E);
    uint*   cntv      = (uint*)alloc(sizeof(uint) * (size_t)n_nodes);
    uint*   startv    = (uint*)alloc(sizeof(uint) * (size_t)n_nodes);
    float*  dis       = (float*)alloc(sizeof(float) * (size_t)n_nodes);
    float*  pooled    = (float*)alloc(sizeof(float) * (size_t)G * 64);
    float*  W_eff     = (float*)alloc(sizeof(float) * F_IN * 64);
    float*  b_eff     = (float*)alloc(sizeof(float) * 64);
    float*  sp        = (float*)alloc(sizeof(float) * 4);
    uint*   spq       = (uint*)alloc(sizeof(uint) * 4);

    hipMemsetAsync(pooled, 0, sizeof(float) * (size_t)G * 64, stream);

    prep_kernel<<<1, 64, 0, stream>>>(msg_w, W_emb, b_emb, W_gcn, sp, spq, W_eff, b_eff);
    // mask pipeline (replaces 3x scattered set_mask)
    m1_hist<<<NMB, 256, 0, stream>>>(known, unk, obs, nk, nu, M, H2, NW, NMB);
    scan_partial_kernel<<<nbL2, 256, 0, stream>>>((const int*)H2, (int*)Hs2, bsum2, L2);
    scan_bsum_kernel<<<1, 64, 0, stream>>>(bsum2, nbL2);
    scan_add_kernel<<<(L2 + 255) / 256, 256, 0, stream>>>((int*)Hs2, bsum2, L2);
    m3_partition<<<NMB, 256, 0, stream>>>(known, unk, obs, nk, nu, M, Hs2, recM, NW, NMB);
    m4_apply<<<NW, 256, 0, stream>>>(recM, Hs2, wclass, E, M, NW, NMB);
    // edge pipeline
    k1_hist<<<NBLK, 256, 0, stream>>>(ei, H, E, NB, NBLK);
    scan_partial_kernel<<<nbL, 256, 0, stream>>>((const int*)H, (int*)Hs, bsum, L);
    scan_bsum_kernel<<<1, 64, 0, stream>>>(bsum, nbL);
    scan_add_kernel<<<(L + 255) / 256, 256, 0, stream>>>((int*)Hs, bsum, L);
    k3_partition<<<NBLK, 256, 0, stream>>>(ei, wclass, Hs, recSorted, E, NB, NBLK);
    k2_stats<<<NB, 256, 0, stream>>>(recSorted, Hs, spq, cntv, startv, dis, E, NB, NBLK, n_nodes);
    h2_kernel<<<(n_nodes + 3) / 4, 256, 0, stream>>>(x, W_eff, b_eff, h2, n_nodes);
    k4_payload<<<NB, 256, 0, stream>>>(recSorted, Hs, sp, dis, startv, payload, E, NB, NBLK, n_nodes);
    gather_pool_kernel<<<(n_nodes + 3) / 4, 256, 0, stream>>>(payload, startv, cntv, dis, h2,
                                                              b_gcn, batch, pooled, n_nodes);
    final_kernel<<<G, 64, 0, stream>>>(pooled, fn_avg, inf_rate, W_fn1, b_fn1,
                                       W_fn2, b_fn2, W_bb1, b_bb1, W_out, b_out, logits);
}

// Round 7
// 271.173 us; speedup vs baseline: 1.2029x; 1.2029x over previous
//
#include <hip/hip_runtime.h>
#include <hip/hip_fp16.h>
#include <math.h>

#define F_IN 12
#define NHID 64
#define HGCN 61
#define EMB_OUT 54
#define SCAN_CH 1024
#define PART_R 8192           // edge records per partition block (LDS-staged)
#define DEG_SCALE 32768.0f    // 2^15 fixed-point for weighted degree
#define NRM_SCALE 32768.0f    // 15-bit fixed-point for norm (norm <= 0.708, never clamps)

typedef unsigned int uint;
typedef unsigned short ushort;
typedef unsigned char uchar;

__device__ __forceinline__ float gelu_exact(float v) {
    return 0.5f * v * (1.0f + erff(v * 0.70710678118654752440f));
}

__device__ __forceinline__ void atomic_add_f32(float* p, float v) {
    unsafeAtomicAdd(p, v);   // hardware global_atomic_add_f32
}

// ---- prep: weight table sp[4] = {1.0 (no mask), softmax0, softmax1, softmax2};
//      spq fixed-point; fold W_emb/b_emb into W_gcn -> W_eff(12x64), b_eff
__global__ void prep_kernel(const float* __restrict__ msg_w,
                            const float* __restrict__ W_emb,
                            const float* __restrict__ b_emb,
                            const float* __restrict__ W_gcn,
                            float* __restrict__ sp, uint* __restrict__ spq,
                            float* __restrict__ W_eff, float* __restrict__ b_eff) {
    __shared__ float ssp[4];
    int t = threadIdx.x;
    if (t == 0) {
        float m = fmaxf(msg_w[0], fmaxf(msg_w[1], msg_w[2]));
        float e0 = expf(msg_w[0] - m), e1 = expf(msg_w[1] - m), e2 = expf(msg_w[2] - m);
        float s = e0 + e1 + e2;
        ssp[0] = 1.0f; ssp[1] = e0 / s; ssp[2] = e1 / s; ssp[3] = e2 / s;
        sp[0] = ssp[0]; sp[1] = ssp[1]; sp[2] = ssp[2]; sp[3] = ssp[3];
    }
    __syncthreads();
    if (t < 4) spq[t] = __float2uint_rn(ssp[t] * DEG_SCALE);
    if (t < HGCN) {
        float be = 0.f, w0 = 0.f, w1 = 0.f;
        for (int k = 0; k < EMB_OUT; ++k) {
            float g = W_gcn[k * HGCN + t];
            be += b_emb[k] * g;
            w0 += W_emb[k] * g;
            w1 += W_emb[EMB_OUT + k] * g;
        }
        b_eff[t] = be;
        W_eff[0 * 64 + t] = w0;
        W_eff[1 * 64 + t] = w1;
        for (int f = 2; f < F_IN; ++f)
            W_eff[f * 64 + t] = W_gcn[(EMB_OUT + f - 2) * HGCN + t];
    }
}

// masks write weight-class bytes; later kernel wins (dispatch order) == torch indexed assign.
// wclass is 3.2MB (L2-resident) -> scattered byte stores are write-back cheap.
__global__ void set_mask_u8(uchar* __restrict__ wclass, const int* __restrict__ mask,
                            uchar v, int n) {
    int i = blockIdx.x * blockDim.x + threadIdx.x;
    if (i < n) wclass[mask[i]] = v;
}

// K1: per-block histogram of destination buckets (col>>8) -> H[bucket*NBLK + blk]
__global__ __launch_bounds__(256) void k1_hist(const int* __restrict__ ei,
                                               uint* __restrict__ H,
                                               int E, int NB, int NBLK) {
    __shared__ uint hist[512];
    int blk = blockIdx.x, t = threadIdx.x;
    hist[t] = 0; hist[t + 256] = 0;
    __syncthreads();
    int lo = blk * PART_R, hi = min(lo + PART_R, E);
    for (int i = lo + t; i < hi; i += 256)
        atomicAdd(&hist[((uint)ei[E + i]) >> 8], 1u);
    __syncthreads();
    for (int b = t; b < NB; b += 256) H[(size_t)b * NBLK + blk] = hist[b];
}

// ---- exclusive scan (3 kernels, generic length)
__global__ void scan_partial_kernel(const int* __restrict__ cnt, int* __restrict__ startv,
                                    int* __restrict__ bsum, int n) {
    __shared__ int s[256];
    int t = threadIdx.x;
    int base = blockIdx.x * SCAN_CH + t * 4;
    int v0 = (base + 0 < n) ? cnt[base + 0] : 0;
    int v1 = (base + 1 < n) ? cnt[base + 1] : 0;
    int v2 = (base + 2 < n) ? cnt[base + 2] : 0;
    int v3 = (base + 3 < n) ? cnt[base + 3] : 0;
    int loc = v0 + v1 + v2 + v3;
    s[t] = loc;
    __syncthreads();
    for (int off = 1; off < 256; off <<= 1) {
        int u = (t >= off) ? s[t - off] : 0;
        __syncthreads();
        s[t] += u;
        __syncthreads();
    }
    int ex = s[t] - loc;
    if (t == 255) bsum[blockIdx.x] = s[255];
    if (base + 0 < n) startv[base + 0] = ex;
    if (base + 1 < n) startv[base + 1] = ex + v0;
    if (base + 2 < n) startv[base + 2] = ex + v0 + v1;
    if (base + 3 < n) startv[base + 3] = ex + v0 + v1 + v2;
}

__global__ void scan_bsum_kernel(int* __restrict__ bsum, int nb) {
    if (threadIdx.x == 0 && blockIdx.x == 0) {
        int acc = 0;
        for (int i = 0; i < nb; ++i) { int v = bsum[i]; bsum[i] = acc; acc += v; }
    }
}

__global__ void scan_add_kernel(int* __restrict__ startv, const int* __restrict__ bsum, int n) {
    int i = blockIdx.x * blockDim.x + threadIdx.x;
    if (i < n) startv[i] += bsum[i / SCAN_CH];
}

// K3: LDS-staged partition to BUCKET granularity.
// Pack rec = row<<10 | (col&255)<<2 | wclass; write bucket-grouped.
__global__ __launch_bounds__(256) void k3_partition(
        const int* __restrict__ ei, const uchar* __restrict__ wclass,
        const uint* __restrict__ Hs, uint* __restrict__ recSorted,
        int E, int NB, int NBLK) {
    __shared__ uint recs[PART_R];
    __shared__ ushort sbkt[PART_R];
    __shared__ uint hist[512];
    __shared__ uint scanA[512];
    __shared__ uint scanB[512];
    __shared__ int  gbase[512];
    __shared__ uint cursor[512];
    int blk = blockIdx.x, t = threadIdx.x;
    int lo = blk * PART_R, hi = min(lo + PART_R, E);
    int cntTot = hi - lo;
    hist[t] = 0; hist[t + 256] = 0;
    __syncthreads();
    for (int i = lo + t; i < hi; i += 256)
        atomicAdd(&hist[((uint)ei[E + i]) >> 8], 1u);
    __syncthreads();
    uint* src = scanA; uint* dst = scanB;
    src[t] = hist[t]; src[t + 256] = hist[t + 256];
    __syncthreads();
    for (int off = 1; off < 512; off <<= 1) {
        dst[t]       = src[t]       + ((t >= off)       ? src[t - off]       : 0u);
        dst[t + 256] = src[t + 256] + ((t + 256 >= off) ? src[t + 256 - off] : 0u);
        __syncthreads();
        uint* tmp = src; src = dst; dst = tmp;
    }
    uint l0 = (t == 0) ? 0u : src[t - 1];
    uint l1 = src[t + 255];
    cursor[t] = l0; cursor[t + 256] = l1;
    if (t < NB)       gbase[t]       = (int)Hs[(size_t)t * NBLK + blk]         - (int)l0;
    if (t + 256 < NB) gbase[t + 256] = (int)Hs[(size_t)(t + 256) * NBLK + blk] - (int)l1;
    __syncthreads();
    for (int i = lo + t; i < hi; i += 256) {
        uint row = (uint)ei[i];
        uint col = (uint)ei[E + i];
        uint b = col >> 8;
        uint rec = (row << 10) | ((col & 255u) << 2) | (uint)wclass[i];
        uint slot = atomicAdd(&cursor[b], 1u);
        recs[slot] = rec;
        sbkt[slot] = (ushort)b;
    }
    __syncthreads();
    for (int s = t; s < cntTot; s += 256)
        recSorted[gbase[sbkt[s]] + s] = recs[s];
}

// K2: per-bucket node stats: cnt, startv (node-exact global CSR offset), dis = rsqrt(deg+1)
__global__ __launch_bounds__(256) void k2_stats(
        const uint* __restrict__ recSorted, const uint* __restrict__ Hs,
        const uint* __restrict__ spq,
        uint* __restrict__ cnt, uint* __restrict__ startv, float* __restrict__ dis,
        int E, int NB, int NBLK, int n_nodes) {
    __shared__ uint hcnt[256], hdeg[256], sA[256], sB[256];
    __shared__ uint sq[4];
    int b = blockIdx.x, t = threadIdx.x;
    hcnt[t] = 0; hdeg[t] = 0;
    if (t < 4) sq[t] = spq[t];
    __syncthreads();
    uint lo = Hs[(size_t)b * NBLK];
    uint hi = (b + 1 < NB) ? Hs[(size_t)(b + 1) * NBLK] : (uint)E;
    for (uint i = lo + t; i < hi; i += 256) {
        uint r = recSorted[i];
        atomicAdd(&hcnt[(r >> 2) & 255u], 1u);
        atomicAdd(&hdeg[(r >> 2) & 255u], sq[r & 3u]);
    }
    __syncthreads();
    uint* src = sA; uint* dst = sB;
    src[t] = hcnt[t];
    __syncthreads();
    for (int off = 1; off < 256; off <<= 1) {
        dst[t] = src[t] + ((t >= off) ? src[t - off] : 0u);
        __syncthreads();
        uint* tmp = src; src = dst; dst = tmp;
    }
    uint excl = (t == 0) ? 0u : src[t - 1];
    int node = (b << 8) + t;
    if (node < n_nodes) {
        cnt[node] = hcnt[t];
        startv[node] = lo + excl;
        float deg = (float)hdeg[t] * (1.0f / DEG_SCALE) + 1.0f;
        dis[node] = rsqrtf(deg);
    }
}

// K4: second-level partition + payload fill. payload = row<<15 | round(norm*32768)
// (row < 2^17, norm <= 0.708 so 15 bits never clamp). Scatter stays in ~32KB window.
__global__ __launch_bounds__(256) void k4_payload(
        const uint* __restrict__ recSorted, const uint* __restrict__ Hs,
        const float* __restrict__ sp, const float* __restrict__ dis,
        const uint* __restrict__ startv,
        uint* __restrict__ payload, int E, int NB, int NBLK, int n_nodes) {
    __shared__ float disl[256];
    __shared__ uint cur[256];
    __shared__ float spl[4];
    int b = blockIdx.x, t = threadIdx.x;
    int node = (b << 8) + t;
    disl[t] = (node < n_nodes) ? dis[node] : 0.0f;
    cur[t]  = (node < n_nodes) ? startv[node] : 0u;
    if (t < 4) spl[t] = sp[t];
    __syncthreads();
    uint lo = Hs[(size_t)b * NBLK];
    uint hi = (b + 1 < NB) ? Hs[(size_t)(b + 1) * NBLK] : (uint)E;
    for (uint i = lo + t; i < hi; i += 256) {
        uint r = recSorted[i];
        uint row = r >> 10;
        uint c = (r >> 2) & 255u;
        float nrm = dis[row] * spl[r & 3u] * disl[c];
        uint pos = atomicAdd(&cur[c], 1u);
        payload[pos] = (row << 15) | __float2uint_rn(nrm * NRM_SCALE);
    }
}

// h2 = x @ W_eff + b_eff, stored fp16 (stride-64 padded, zeros at d>=61)
__global__ void h2_kernel(const float* __restrict__ x, const float* __restrict__ W_eff,
                          const float* __restrict__ b_eff,
                          __half* __restrict__ h2, int n_nodes) {
    int node = blockIdx.x * 4 + (threadIdx.x >> 6);
    int d = threadIdx.x & 63;
    if (node >= n_nodes) return;
    float v = 0.f;
    if (d < HGCN) {
        v = b_eff[d];
#pragma unroll
        for (int f = 0; f < F_IN; ++f)
            v += x[node * F_IN + f] * W_eff[f * 64 + d];
    }
    h2[node * 64 + d] = __float2half(v);
}

// gather (one wave per destination node) + gelu + pool, fused; 8 loads in flight
__global__ void gather_pool_kernel(const uint* __restrict__ payload,
                                   const uint* __restrict__ startv, const uint* __restrict__ cnt,
                                   const float* __restrict__ dis, const __half* __restrict__ h2,
                                   const float* __restrict__ b_gcn, const int* __restrict__ batch,
                                   float* __restrict__ pooled, int n_nodes) {
    int node = blockIdx.x * 4 + (threadIdx.x >> 6);
    int d = threadIdx.x & 63;
    if (node >= n_nodes) return;
    int s = (int)startv[node];
    int m = (int)cnt[node];
    float di = dis[node];
    float acc = di * di * __half2float(h2[node * 64 + d]);   // self-loop term
    const float inv = 1.0f / NRM_SCALE;
    for (int j0 = 0; j0 < m; j0 += 64) {
        uint p = 0;
        if (j0 + d < m) p = payload[s + j0 + d];  // coalesced 256B load
        int lim = min(64, m - j0);
        int k = 0;
        for (; k + 8 <= lim; k += 8) {            // 8 independent loads in flight
            uint p0 = __shfl(p, k),     p1 = __shfl(p, k + 1);
            uint p2 = __shfl(p, k + 2), p3 = __shfl(p, k + 3);
            uint p4 = __shfl(p, k + 4), p5 = __shfl(p, k + 5);
            uint p6 = __shfl(p, k + 6), p7 = __shfl(p, k + 7);
            float h0 = __half2float(h2[(p0 >> 15) * 64 + d]);
            float h1 = __half2float(h2[(p1 >> 15) * 64 + d]);
            float h2v = __half2float(h2[(p2 >> 15) * 64 + d]);
            float h3 = __half2float(h2[(p3 >> 15) * 64 + d]);
            float h4 = __half2float(h2[(p4 >> 15) * 64 + d]);
            float h5 = __half2float(h2[(p5 >> 15) * 64 + d]);
            float h6 = __half2float(h2[(p6 >> 15) * 64 + d]);
            float h7 = __half2float(h2[(p7 >> 15) * 64 + d]);
            acc += (float)(p0 & 32767u) * inv * h0;
            acc += (float)(p1 & 32767u) * inv * h1;
            acc += (float)(p2 & 32767u) * inv * h2v;
            acc += (float)(p3 & 32767u) * inv * h3;
            acc += (float)(p4 & 32767u) * inv * h4;
            acc += (float)(p5 & 32767u) * inv * h5;
            acc += (float)(p6 & 32767u) * inv * h6;
            acc += (float)(p7 & 32767u) * inv * h7;
        }
        for (; k < lim; ++k) {
            uint pk = __shfl(p, k);
            acc += (float)(pk & 32767u) * inv * __half2float(h2[(pk >> 15) * 64 + d]);
        }
    }
    if (d < HGCN) {
        float v = gelu_exact(acc + b_gcn[d]);
        atomic_add_f32(&pooled[batch[node] * 64 + d], v);
    }
}

// per-graph head
__global__ void final_kernel(const float* __restrict__ pooled,
                             const float* __restrict__ fn_avg,
                             const float* __restrict__ inf_rate,
                             const float* __restrict__ W_fn1, const float* __restrict__ b_fn1,
                             const float* __restrict__ W_fn2, const float* __restrict__ b_fn2,
                             const float* __restrict__ W_bb1, const float* __restrict__ b_bb1,
                             const float* __restrict__ W_out, const float* __restrict__ b_out,
                             float* __restrict__ logits) {
    __shared__ float z[64];
    __shared__ float t1[16];
    int g = blockIdx.x;
    int t = threadIdx.x;
    if (t < HGCN) z[t] = pooled[g * 64 + t];
    float e0 = fn_avg[g * 2], e1 = fn_avg[g * 2 + 1], e2 = inf_rate[g];
    if (t < 16) {
        float a = e0 * W_fn1[t] + e1 * W_fn1[16 + t] + e2 * W_fn1[32 + t] + b_fn1[t];
        t1[t] = gelu_exact(a);
    }
    __syncthreads();
    if (t < 3) {
        float a = b_fn2[t];
#pragma unroll
        for (int k = 0; k < 16; ++k) a += t1[k] * W_fn2[k * 3 + t];
        z[HGCN + t] = a;
    }
    __syncthreads();
    float acc = b_bb1[t];
#pragma unroll 8
    for (int k = 0; k < 64; ++k) acc += z[k] * W_bb1[k * 64 + t];
    float p = gelu_exact(acc) * W_out[t];
#pragma unroll
    for (int off = 32; off > 0; off >>= 1) p += __shfl_down(p, off);
    if (t == 0) logits[g] = p + b_out[0];
}

extern "C" void kernel_launch(void* const* d_in, const int* in_sizes, int n_in,
                              void* d_out, int out_size, void* d_ws, size_t ws_size,
                              hipStream_t stream) {
    const float* x        = (const float*)d_in[0];
    const int*   ei       = (const int*)d_in[1];
    const int*   batch    = (const int*)d_in[2];
    const int*   known    = (const int*)d_in[3];
    const int*   unk      = (const int*)d_in[4];
    const int*   obs      = (const int*)d_in[5];
    const float* fn_avg   = (const float*)d_in[6];
    const float* inf_rate = (const float*)d_in[7];
    const float* msg_w    = (const float*)d_in[8];
    const float* W_emb    = (const float*)d_in[9];
    const float* b_emb    = (const float*)d_in[10];
    const float* W_gcn    = (const float*)d_in[11];
    const float* b_gcn    = (const float*)d_in[12];
    const float* W_fn1    = (const float*)d_in[13];
    const float* b_fn1    = (const float*)d_in[14];
    const float* W_fn2    = (const float*)d_in[15];
    const float* b_fn2    = (const float*)d_in[16];
    const float* W_bb1    = (const float*)d_in[17];
    const float* b_bb1    = (const float*)d_in[18];
    const float* W_out    = (const float*)d_in[19];
    const float* b_out    = (const float*)d_in[20];
    float* logits = (float*)d_out;

    const int n_nodes = in_sizes[0] / F_IN;
    const int E       = in_sizes[1] / 2;
    const int nk = in_sizes[3], nu = in_sizes[4], no = in_sizes[5];
    const int G = in_sizes[6] / 2;

    const int NB   = (n_nodes + 255) >> 8;
    const int NBLK = (E + PART_R - 1) / PART_R;
    const int L    = NB * NBLK;
    const int nbL  = (L + SCAN_CH - 1) / SCAN_CH;

    char* ws = (char*)d_ws;
    size_t off = 0;
    auto alloc = [&](size_t bytes) -> void* {
        void* p = ws + off;
        off += (bytes + 255) & ~size_t(255);
        return p;
    };
    uchar*  wclass    = (uchar*)alloc(sizeof(uchar) * (size_t)E);
    uint*   recSorted = (uint*)alloc(sizeof(uint) * (size_t)E);
    uint*   H         = (uint*)alloc(sizeof(uint) * (size_t)L);
    uint*   Hs        = (uint*)alloc(sizeof(uint) * (size_t)L);
    int*    bsum      = (int*)alloc(sizeof(int) * (size_t)(nbL + 1));
    __half* h2        = (__half*)alloc(sizeof(__half) * (size_t)n_nodes * 64);
    uint*   payload   = (uint*)alloc(sizeof(uint) * (size_t)E);
    uint*   cntv      = (uint*)alloc(sizeof(uint) * (size_t)n_nodes);
    uint*   startv    = (uint*)alloc(sizeof(uint) * (size_t)n_nodes);
    float*  dis       = (float*)alloc(sizeof(float) * (size_t)n_nodes);
    float*  pooled    = (float*)alloc(sizeof(float) * (size_t)G * 64);
    float*  W_eff     = (float*)alloc(sizeof(float) * F_IN * 64);
    float*  b_eff     = (float*)alloc(sizeof(float) * 64);
    float*  sp        = (float*)alloc(sizeof(float) * 4);
    uint*   spq       = (uint*)alloc(sizeof(uint) * 4);

    hipMemsetAsync(wclass, 0, sizeof(uchar) * (size_t)E, stream);   // class 0 = weight 1.0
    hipMemsetAsync(pooled, 0, sizeof(float) * (size_t)G * 64, stream);

    prep_kernel<<<1, 64, 0, stream>>>(msg_w, W_emb, b_emb, W_gcn, sp, spq, W_eff, b_eff);
    set_mask_u8<<<(nk + 255) / 256, 256, 0, stream>>>(wclass, known, 1, nk);
    set_mask_u8<<<(nu + 255) / 256, 256, 0, stream>>>(wclass, unk, 2, nu);
    set_mask_u8<<<(no + 255) / 256, 256, 0, stream>>>(wclass, obs, 3, no);
    k1_hist<<<NBLK, 256, 0, stream>>>(ei, H, E, NB, NBLK);
    scan_partial_kernel<<<nbL, 256, 0, stream>>>((const int*)H, (int*)Hs, bsum, L);
    scan_bsum_kernel<<<1, 64, 0, stream>>>(bsum, nbL);
    scan_add_kernel<<<(L + 255) / 256, 256, 0, stream>>>((int*)Hs, bsum, L);
    k3_partition<<<NBLK, 256, 0, stream>>>(ei, wclass, Hs, recSorted, E, NB, NBLK);
    k2_stats<<<NB, 256, 0, stream>>>(recSorted, Hs, spq, cntv, startv, dis, E, NB, NBLK, n_nodes);
    h2_kernel<<<(n_nodes + 3) / 4, 256, 0, stream>>>(x, W_eff, b_eff, h2, n_nodes);
    k4_payload<<<NB, 256, 0, stream>>>(recSorted, Hs, sp, dis, startv, payload, E, NB, NBLK, n_nodes);
    gather_pool_kernel<<<(n_nodes + 3) / 4, 256, 0, stream>>>(payload, startv, cntv, dis, h2,
                                                              b_gcn, batch, pooled, n_nodes);
    final_kernel<<<G, 64, 0, stream>>>(pooled, fn_avg, inf_rate, W_fn1, b_fn1,
                                       W_fn2, b_fn2, W_bb1, b_bb1, W_out, b_out, logits);
}

// Round 8
// 256.305 us; speedup vs baseline: 1.2727x; 1.0580x over previous
//
#include <hip/hip_runtime.h>
#include <hip/hip_fp16.h>
#include <math.h>

#define F_IN 12
#define NHID 64
#define HGCN 61
#define EMB_OUT 54
#define SCAN_CH 1024
#define PART_R 8192           // edge records per partition block (LDS-staged)
#define DEG_SCALE 32768.0f    // 2^15 fixed-point for weighted degree
#define NRM_SCALE 32768.0f    // 15-bit fixed-point for norm (norm <= 0.708, never clamps)

typedef unsigned int uint;
typedef unsigned short ushort;
typedef unsigned char uchar;

__device__ __forceinline__ float gelu_exact(float v) {
    return 0.5f * v * (1.0f + erff(v * 0.70710678118654752440f));
}

__device__ __forceinline__ void atomic_add_f32(float* p, float v) {
    unsafeAtomicAdd(p, v);   // hardware global_atomic_add_f32
}

// ---- prep: weight table sp[4] = {1.0 (no mask), softmax0, softmax1, softmax2};
//      spq fixed-point; fold W_emb/b_emb into W_gcn -> W_eff(12x64), b_eff
__global__ void prep_kernel(const float* __restrict__ msg_w,
                            const float* __restrict__ W_emb,
                            const float* __restrict__ b_emb,
                            const float* __restrict__ W_gcn,
                            float* __restrict__ sp, uint* __restrict__ spq,
                            float* __restrict__ W_eff, float* __restrict__ b_eff) {
    __shared__ float ssp[4];
    int t = threadIdx.x;
    if (t == 0) {
        float m = fmaxf(msg_w[0], fmaxf(msg_w[1], msg_w[2]));
        float e0 = expf(msg_w[0] - m), e1 = expf(msg_w[1] - m), e2 = expf(msg_w[2] - m);
        float s = e0 + e1 + e2;
        ssp[0] = 1.0f; ssp[1] = e0 / s; ssp[2] = e1 / s; ssp[3] = e2 / s;
        sp[0] = ssp[0]; sp[1] = ssp[1]; sp[2] = ssp[2]; sp[3] = ssp[3];
    }
    __syncthreads();
    if (t < 4) spq[t] = __float2uint_rn(ssp[t] * DEG_SCALE);
    if (t < HGCN) {
        float be = 0.f, w0 = 0.f, w1 = 0.f;
        for (int k = 0; k < EMB_OUT; ++k) {
            float g = W_gcn[k * HGCN + t];
            be += b_emb[k] * g;
            w0 += W_emb[k] * g;
            w1 += W_emb[EMB_OUT + k] * g;
        }
        b_eff[t] = be;
        W_eff[0 * 64 + t] = w0;
        W_eff[1 * 64 + t] = w1;
        for (int f = 2; f < F_IN; ++f)
            W_eff[f * 64 + t] = W_gcn[(EMB_OUT + f - 2) * HGCN + t];
    }
}

// masks write weight-class bytes; later kernel wins (dispatch order) == torch indexed assign.
__global__ void set_mask_u8(uchar* __restrict__ wclass, const int* __restrict__ mask,
                            uchar v, int n) {
    int i = blockIdx.x * blockDim.x + threadIdx.x;
    if (i < n) wclass[mask[i]] = v;
}

// K1: per-block histogram of destination buckets (col>>8) -> H[bucket*NBLK + blk]
__global__ __launch_bounds__(256) void k1_hist(const int* __restrict__ ei,
                                               uint* __restrict__ H,
                                               int E, int NB, int NBLK) {
    __shared__ uint hist[512];
    int blk = blockIdx.x, t = threadIdx.x;
    hist[t] = 0; hist[t + 256] = 0;
    __syncthreads();
    int lo = blk * PART_R, hi = min(lo + PART_R, E);
    for (int i = lo + t; i < hi; i += 256)
        atomicAdd(&hist[((uint)ei[E + i]) >> 8], 1u);
    __syncthreads();
    for (int b = t; b < NB; b += 256) H[(size_t)b * NBLK + blk] = hist[b];
}

// ---- exclusive scan (3 kernels, generic length)
__global__ void scan_partial_kernel(const int* __restrict__ cnt, int* __restrict__ startv,
                                    int* __restrict__ bsum, int n) {
    __shared__ int s[256];
    int t = threadIdx.x;
    int base = blockIdx.x * SCAN_CH + t * 4;
    int v0 = (base + 0 < n) ? cnt[base + 0] : 0;
    int v1 = (base + 1 < n) ? cnt[base + 1] : 0;
    int v2 = (base + 2 < n) ? cnt[base + 2] : 0;
    int v3 = (base + 3 < n) ? cnt[base + 3] : 0;
    int loc = v0 + v1 + v2 + v3;
    s[t] = loc;
    __syncthreads();
    for (int off = 1; off < 256; off <<= 1) {
        int u = (t >= off) ? s[t - off] : 0;
        __syncthreads();
        s[t] += u;
        __syncthreads();
    }
    int ex = s[t] - loc;
    if (t == 255) bsum[blockIdx.x] = s[255];
    if (base + 0 < n) startv[base + 0] = ex;
    if (base + 1 < n) startv[base + 1] = ex + v0;
    if (base + 2 < n) startv[base + 2] = ex + v0 + v1;
    if (base + 3 < n) startv[base + 3] = ex + v0 + v1 + v2;
}

__global__ void scan_bsum_kernel(int* __restrict__ bsum, int nb) {
    if (threadIdx.x == 0 && blockIdx.x == 0) {
        int acc = 0;
        for (int i = 0; i < nb; ++i) { int v = bsum[i]; bsum[i] = acc; acc += v; }
    }
}

__global__ void scan_add_kernel(int* __restrict__ startv, const int* __restrict__ bsum, int n) {
    int i = blockIdx.x * blockDim.x + threadIdx.x;
    if (i < n) startv[i] += bsum[i / SCAN_CH];
}

// K3: LDS-staged partition to BUCKET granularity.
// Pack rec = row<<10 | (col&255)<<2 | wclass; write bucket-grouped.
__global__ __launch_bounds__(256) void k3_partition(
        const int* __restrict__ ei, const uchar* __restrict__ wclass,
        const uint* __restrict__ Hs, uint* __restrict__ recSorted,
        int E, int NB, int NBLK) {
    __shared__ uint recs[PART_R];
    __shared__ ushort sbkt[PART_R];
    __shared__ uint hist[512];
    __shared__ uint scanA[512];
    __shared__ uint scanB[512];
    __shared__ int  gbase[512];
    __shared__ uint cursor[512];
    int blk = blockIdx.x, t = threadIdx.x;
    int lo = blk * PART_R, hi = min(lo + PART_R, E);
    int cntTot = hi - lo;
    hist[t] = 0; hist[t + 256] = 0;
    __syncthreads();
    for (int i = lo + t; i < hi; i += 256)
        atomicAdd(&hist[((uint)ei[E + i]) >> 8], 1u);
    __syncthreads();
    uint* src = scanA; uint* dst = scanB;
    src[t] = hist[t]; src[t + 256] = hist[t + 256];
    __syncthreads();
    for (int off = 1; off < 512; off <<= 1) {
        dst[t]       = src[t]       + ((t >= off)       ? src[t - off]       : 0u);
        dst[t + 256] = src[t + 256] + ((t + 256 >= off) ? src[t + 256 - off] : 0u);
        __syncthreads();
        uint* tmp = src; src = dst; dst = tmp;
    }
    uint l0 = (t == 0) ? 0u : src[t - 1];
    uint l1 = src[t + 255];
    cursor[t] = l0; cursor[t + 256] = l1;
    if (t < NB)       gbase[t]       = (int)Hs[(size_t)t * NBLK + blk]         - (int)l0;
    if (t + 256 < NB) gbase[t + 256] = (int)Hs[(size_t)(t + 256) * NBLK + blk] - (int)l1;
    __syncthreads();
    for (int i = lo + t; i < hi; i += 256) {
        uint row = (uint)ei[i];
        uint col = (uint)ei[E + i];
        uint b = col >> 8;
        uint rec = (row << 10) | ((col & 255u) << 2) | (uint)wclass[i];
        uint slot = atomicAdd(&cursor[b], 1u);
        recs[slot] = rec;
        sbkt[slot] = (ushort)b;
    }
    __syncthreads();
    for (int s = t; s < cntTot; s += 256)
        recSorted[gbase[sbkt[s]] + s] = recs[s];
}

// K2: per-bucket node stats: cnt, startv (node-exact global CSR offset), dis = rsqrt(deg+1)
__global__ __launch_bounds__(256) void k2_stats(
        const uint* __restrict__ recSorted, const uint* __restrict__ Hs,
        const uint* __restrict__ spq,
        uint* __restrict__ cnt, uint* __restrict__ startv, float* __restrict__ dis,
        int E, int NB, int NBLK, int n_nodes) {
    __shared__ uint hcnt[256], hdeg[256], sA[256], sB[256];
    __shared__ uint sq[4];
    int b = blockIdx.x, t = threadIdx.x;
    hcnt[t] = 0; hdeg[t] = 0;
    if (t < 4) sq[t] = spq[t];
    __syncthreads();
    uint lo = Hs[(size_t)b * NBLK];
    uint hi = (b + 1 < NB) ? Hs[(size_t)(b + 1) * NBLK] : (uint)E;
    for (uint i = lo + t; i < hi; i += 256) {
        uint r = recSorted[i];
        atomicAdd(&hcnt[(r >> 2) & 255u], 1u);
        atomicAdd(&hdeg[(r >> 2) & 255u], sq[r & 3u]);
    }
    __syncthreads();
    uint* src = sA; uint* dst = sB;
    src[t] = hcnt[t];
    __syncthreads();
    for (int off = 1; off < 256; off <<= 1) {
        dst[t] = src[t] + ((t >= off) ? src[t - off] : 0u);
        __syncthreads();
        uint* tmp = src; src = dst; dst = tmp;
    }
    uint excl = (t == 0) ? 0u : src[t - 1];
    int node = (b << 8) + t;
    if (node < n_nodes) {
        cnt[node] = hcnt[t];
        startv[node] = lo + excl;
        float deg = (float)hdeg[t] * (1.0f / DEG_SCALE) + 1.0f;
        dis[node] = rsqrtf(deg);
    }
}

// K4: second-level partition + payload fill. payload = row<<15 | round(norm*32768)
__global__ __launch_bounds__(256) void k4_payload(
        const uint* __restrict__ recSorted, const uint* __restrict__ Hs,
        const float* __restrict__ sp, const float* __restrict__ dis,
        const uint* __restrict__ startv,
        uint* __restrict__ payload, int E, int NB, int NBLK, int n_nodes) {
    __shared__ float disl[256];
    __shared__ uint cur[256];
    __shared__ float spl[4];
    int b = blockIdx.x, t = threadIdx.x;
    int node = (b << 8) + t;
    disl[t] = (node < n_nodes) ? dis[node] : 0.0f;
    cur[t]  = (node < n_nodes) ? startv[node] : 0u;
    if (t < 4) spl[t] = sp[t];
    __syncthreads();
    uint lo = Hs[(size_t)b * NBLK];
    uint hi = (b + 1 < NB) ? Hs[(size_t)(b + 1) * NBLK] : (uint)E;
    for (uint i = lo + t; i < hi; i += 256) {
        uint r = recSorted[i];
        uint row = r >> 10;
        uint c = (r >> 2) & 255u;
        float nrm = dis[row] * spl[r & 3u] * disl[c];
        uint pos = atomicAdd(&cur[c], 1u);
        payload[pos] = (row << 15) | __float2uint_rn(nrm * NRM_SCALE);
    }
}

// h2 = x @ W_eff + b_eff, stored fp16 (stride-64 padded, zeros at d>=61)
__global__ void h2_kernel(const float* __restrict__ x, const float* __restrict__ W_eff,
                          const float* __restrict__ b_eff,
                          __half* __restrict__ h2, int n_nodes) {
    int node = blockIdx.x * 4 + (threadIdx.x >> 6);
    int d = threadIdx.x & 63;
    if (node >= n_nodes) return;
    float v = 0.f;
    if (d < HGCN) {
        v = b_eff[d];
#pragma unroll
        for (int f = 0; f < F_IN; ++f)
            v += x[node * F_IN + f] * W_eff[f * 64 + d];
    }
    h2[node * 64 + d] = __float2half(v);
}

// gather + gelu + pool, fused. 2 edges/wave in parallel: group g = lane>>5 handles
// edge 2k+g; each lane owns a dim PAIR via one half2 (4B) load. Out-of-range shfl
// sources carry p=0 -> row=0, w=0 (harmless), so the tail is branch-free.
__global__ void gather_pool_kernel(const uint* __restrict__ payload,
                                   const uint* __restrict__ startv, const uint* __restrict__ cnt,
                                   const float* __restrict__ dis,
                                   const __half2* __restrict__ h2v,
                                   const float* __restrict__ b_gcn, const int* __restrict__ batch,
                                   float* __restrict__ pooled, int n_nodes) {
    int node = blockIdx.x * 4 + (threadIdx.x >> 6);
    int lane = threadIdx.x & 63;
    int g = lane >> 5;          // edge-parity group
    int sub = lane & 31;        // dim pair index (dims 2*sub, 2*sub+1)
    if (node >= n_nodes) return;
    int s = (int)startv[node];
    int m = (int)cnt[node];
    const float inv = 1.0f / NRM_SCALE;
    float accx = 0.f, accy = 0.f;
    if (g == 0) {               // self-loop term only in group 0 (avoid double count)
        float di = dis[node];
        float2 hv = __half22float2(h2v[node * 32 + sub]);
        accx = di * di * hv.x;
        accy = di * di * hv.y;
    }
    for (int j0 = 0; j0 < m; j0 += 64) {
        uint p = 0;
        if (j0 + lane < m) p = payload[s + j0 + lane];  // coalesced 256B chunk load
        int lim = min(64, m - j0);
        int npairs = (lim + 1) >> 1;
        int k = 0;
        for (; k + 4 <= npairs; k += 4) {               // 4 loads in flight per group
            uint p0 = __shfl(p, 2 * (k + 0) + g);
            uint p1 = __shfl(p, 2 * (k + 1) + g);
            uint p2 = __shfl(p, 2 * (k + 2) + g);
            uint p3 = __shfl(p, 2 * (k + 3) + g);
            float2 h0 = __half22float2(h2v[(p0 >> 15) * 32 + sub]);
            float2 h1 = __half22float2(h2v[(p1 >> 15) * 32 + sub]);
            float2 h2f = __half22float2(h2v[(p2 >> 15) * 32 + sub]);
            float2 h3 = __half22float2(h2v[(p3 >> 15) * 32 + sub]);
            float w0 = (float)(p0 & 32767u) * inv;
            float w1 = (float)(p1 & 32767u) * inv;
            float w2 = (float)(p2 & 32767u) * inv;
            float w3 = (float)(p3 & 32767u) * inv;
            accx += w0 * h0.x; accy += w0 * h0.y;
            accx += w1 * h1.x; accy += w1 * h1.y;
            accx += w2 * h2f.x; accy += w2 * h2f.y;
            accx += w3 * h3.x; accy += w3 * h3.y;
        }
        for (; k < npairs; ++k) {
            uint pk = __shfl(p, 2 * k + g);
            float2 hk = __half22float2(h2v[(pk >> 15) * 32 + sub]);
            float wk = (float)(pk & 32767u) * inv;
            accx += wk * hk.x; accy += wk * hk.y;
        }
    }
    // combine the two edge-parity groups: lane s and lane s+32 hold partials of same dims
    accx += __shfl_xor(accx, 32);
    accy += __shfl_xor(accy, 32);
    // epilogue: group 0 writes even dim, group 1 writes odd dim
    int d = 2 * sub + g;
    float val = g ? accy : accx;
    if (d < HGCN) {
        float v = gelu_exact(val + b_gcn[d]);
        atomic_add_f32(&pooled[batch[node] * 64 + d], v);
    }
}

// per-graph head
__global__ void final_kernel(const float* __restrict__ pooled,
                             const float* __restrict__ fn_avg,
                             const float* __restrict__ inf_rate,
                             const float* __restrict__ W_fn1, const float* __restrict__ b_fn1,
                             const float* __restrict__ W_fn2, const float* __restrict__ b_fn2,
                             const float* __restrict__ W_bb1, const float* __restrict__ b_bb1,
                             const float* __restrict__ W_out, const float* __restrict__ b_out,
                             float* __restrict__ logits) {
    __shared__ float z[64];
    __shared__ float t1[16];
    int g = blockIdx.x;
    int t = threadIdx.x;
    if (t < HGCN) z[t] = pooled[g * 64 + t];
    float e0 = fn_avg[g * 2], e1 = fn_avg[g * 2 + 1], e2 = inf_rate[g];
    if (t < 16) {
        float a = e0 * W_fn1[t] + e1 * W_fn1[16 + t] + e2 * W_fn1[32 + t] + b_fn1[t];
        t1[t] = gelu_exact(a);
    }
    __syncthreads();
    if (t < 3) {
        float a = b_fn2[t];
#pragma unroll
        for (int k = 0; k < 16; ++k) a += t1[k] * W_fn2[k * 3 + t];
        z[HGCN + t] = a;
    }
    __syncthreads();
    float acc = b_bb1[t];
#pragma unroll 8
    for (int k = 0; k < 64; ++k) acc += z[k] * W_bb1[k * 64 + t];
    float p = gelu_exact(acc) * W_out[t];
#pragma unroll
    for (int off = 32; off > 0; off >>= 1) p += __shfl_down(p, off);
    if (t == 0) logits[g] = p + b_out[0];
}

extern "C" void kernel_launch(void* const* d_in, const int* in_sizes, int n_in,
                              void* d_out, int out_size, void* d_ws, size_t ws_size,
                              hipStream_t stream) {
    const float* x        = (const float*)d_in[0];
    const int*   ei       = (const int*)d_in[1];
    const int*   batch    = (const int*)d_in[2];
    const int*   known    = (const int*)d_in[3];
    const int*   unk      = (const int*)d_in[4];
    const int*   obs      = (const int*)d_in[5];
    const float* fn_avg   = (const float*)d_in[6];
    const float* inf_rate = (const float*)d_in[7];
    const float* msg_w    = (const float*)d_in[8];
    const float* W_emb    = (const float*)d_in[9];
    const float* b_emb    = (const float*)d_in[10];
    const float* W_gcn    = (const float*)d_in[11];
    const float* b_gcn    = (const float*)d_in[12];
    const float* W_fn1    = (const float*)d_in[13];
    const float* b_fn1    = (const float*)d_in[14];
    const float* W_fn2    = (const float*)d_in[15];
    const float* b_fn2    = (const float*)d_in[16];
    const float* W_bb1    = (const float*)d_in[17];
    const float* b_bb1    = (const float*)d_in[18];
    const float* W_out    = (const float*)d_in[19];
    const float* b_out    = (const float*)d_in[20];
    float* logits = (float*)d_out;

    const int n_nodes = in_sizes[0] / F_IN;
    const int E       = in_sizes[1] / 2;
    const int nk = in_sizes[3], nu = in_sizes[4], no = in_sizes[5];
    const int G = in_sizes[6] / 2;

    const int NB   = (n_nodes + 255) >> 8;
    const int NBLK = (E + PART_R - 1) / PART_R;
    const int L    = NB * NBLK;
    const int nbL  = (L + SCAN_CH - 1) / SCAN_CH;

    char* ws = (char*)d_ws;
    size_t off = 0;
    auto alloc = [&](size_t bytes) -> void* {
        void* p = ws + off;
        off += (bytes + 255) & ~size_t(255);
        return p;
    };
    uchar*  wclass    = (uchar*)alloc(sizeof(uchar) * (size_t)E);
    uint*   recSorted = (uint*)alloc(sizeof(uint) * (size_t)E);
    uint*   H         = (uint*)alloc(sizeof(uint) * (size_t)L);
    uint*   Hs        = (uint*)alloc(sizeof(uint) * (size_t)L);
    int*    bsum      = (int*)alloc(sizeof(int) * (size_t)(nbL + 1));
    __half* h2        = (__half*)alloc(sizeof(__half) * (size_t)n_nodes * 64);
    uint*   payload   = (uint*)alloc(sizeof(uint) * (size_t)E);
    uint*   cntv      = (uint*)alloc(sizeof(uint) * (size_t)n_nodes);
    uint*   startv    = (uint*)alloc(sizeof(uint) * (size_t)n_nodes);
    float*  dis       = (float*)alloc(sizeof(float) * (size_t)n_nodes);
    float*  pooled    = (float*)alloc(sizeof(float) * (size_t)G * 64);
    float*  W_eff     = (float*)alloc(sizeof(float) * F_IN * 64);
    float*  b_eff     = (float*)alloc(sizeof(float) * 64);
    float*  sp        = (float*)alloc(sizeof(float) * 4);
    uint*   spq       = (uint*)alloc(sizeof(uint) * 4);

    hipMemsetAsync(wclass, 0, sizeof(uchar) * (size_t)E, stream);   // class 0 = weight 1.0
    hipMemsetAsync(pooled, 0, sizeof(float) * (size_t)G * 64, stream);

    prep_kernel<<<1, 64, 0, stream>>>(msg_w, W_emb, b_emb, W_gcn, sp, spq, W_eff, b_eff);
    set_mask_u8<<<(nk + 255) / 256, 256, 0, stream>>>(wclass, known, 1, nk);
    set_mask_u8<<<(nu + 255) / 256, 256, 0, stream>>>(wclass, unk, 2, nu);
    set_mask_u8<<<(no + 255) / 256, 256, 0, stream>>>(wclass, obs, 3, no);
    k1_hist<<<NBLK, 256, 0, stream>>>(ei, H, E, NB, NBLK);
    scan_partial_kernel<<<nbL, 256, 0, stream>>>((const int*)H, (int*)Hs, bsum, L);
    scan_bsum_kernel<<<1, 64, 0, stream>>>(bsum, nbL);
    scan_add_kernel<<<(L + 255) / 256, 256, 0, stream>>>((int*)Hs, bsum, L);
    k3_partition<<<NBLK, 256, 0, stream>>>(ei, wclass, Hs, recSorted, E, NB, NBLK);
    k2_stats<<<NB, 256, 0, stream>>>(recSorted, Hs, spq, cntv, startv, dis, E, NB, NBLK, n_nodes);
    h2_kernel<<<(n_nodes + 3) / 4, 256, 0, stream>>>(x, W_eff, b_eff, h2, n_nodes);
    k4_payload<<<NB, 256, 0, stream>>>(recSorted, Hs, sp, dis, startv, payload, E, NB, NBLK, n_nodes);
    gather_pool_kernel<<<(n_nodes + 3) / 4, 256, 0, stream>>>(payload, startv, cntv, dis,
                                                              (const __half2*)h2, b_gcn, batch,
                                                              pooled, n_nodes);
    final_kernel<<<G, 64, 0, stream>>>(pooled, fn_avg, inf_rate, W_fn1, b_fn1,
                                       W_fn2, b_fn2, W_bb1, b_bb1, W_out, b_out, logits);
}

// Round 9
// 241.888 us; speedup vs baseline: 1.3486x; 1.0596x over previous
//
#include <hip/hip_runtime.h>
#include <hip/hip_fp16.h>
#include <math.h>

#define F_IN 12
#define NHID 64
#define HGCN 61
#define EMB_OUT 54
#define SCAN_CH 1024
#define PART_R 8192           // edge records per partition block (LDS-staged)
#define DEG_SCALE 32768.0f    // 2^15 fixed-point for weighted degree
#define NRM_SCALE 32768.0f    // 15-bit fixed-point for norm (norm <= 0.708, never clamps)

typedef unsigned int uint;
typedef unsigned short ushort;
typedef unsigned char uchar;

__device__ __forceinline__ float gelu_exact(float v) {
    return 0.5f * v * (1.0f + erff(v * 0.70710678118654752440f));
}

__device__ __forceinline__ void atomic_add_f32(float* p, float v) {
    unsafeAtomicAdd(p, v);   // hardware global_atomic_add_f32
}

// ---- prep: weight table sp[4] = {1.0 (no mask), softmax0, softmax1, softmax2};
//      spq fixed-point; fold W_emb/b_emb into W_gcn -> W_eff(12x64), b_eff
__global__ void prep_kernel(const float* __restrict__ msg_w,
                            const float* __restrict__ W_emb,
                            const float* __restrict__ b_emb,
                            const float* __restrict__ W_gcn,
                            float* __restrict__ sp, uint* __restrict__ spq,
                            float* __restrict__ W_eff, float* __restrict__ b_eff) {
    __shared__ float ssp[4];
    int t = threadIdx.x;
    if (t == 0) {
        float m = fmaxf(msg_w[0], fmaxf(msg_w[1], msg_w[2]));
        float e0 = expf(msg_w[0] - m), e1 = expf(msg_w[1] - m), e2 = expf(msg_w[2] - m);
        float s = e0 + e1 + e2;
        ssp[0] = 1.0f; ssp[1] = e0 / s; ssp[2] = e1 / s; ssp[3] = e2 / s;
        sp[0] = ssp[0]; sp[1] = ssp[1]; sp[2] = ssp[2]; sp[3] = ssp[3];
    }
    __syncthreads();
    if (t < 4) spq[t] = __float2uint_rn(ssp[t] * DEG_SCALE);
    if (t < HGCN) {
        float be = 0.f, w0 = 0.f, w1 = 0.f;
        for (int k = 0; k < EMB_OUT; ++k) {
            float g = W_gcn[k * HGCN + t];
            be += b_emb[k] * g;
            w0 += W_emb[k] * g;
            w1 += W_emb[EMB_OUT + k] * g;
        }
        b_eff[t] = be;
        W_eff[0 * 64 + t] = w0;
        W_eff[1 * 64 + t] = w1;
        for (int f = 2; f < F_IN; ++f)
            W_eff[f * 64 + t] = W_gcn[(EMB_OUT + f - 2) * HGCN + t];
    }
}

// masks write weight-class bytes; later kernel wins (dispatch order) == torch indexed assign.
__global__ void set_mask_u8(uchar* __restrict__ wclass, const int* __restrict__ mask,
                            uchar v, int n) {
    int i = blockIdx.x * blockDim.x + threadIdx.x;
    if (i < n) wclass[mask[i]] = v;
}

// K1: per-block histogram of destination buckets (col>>8) -> H[bucket*NBLK + blk].
// Also zero-inits wclass (runs BEFORE set_mask kernels).
__global__ __launch_bounds__(256) void k1_hist(const int* __restrict__ ei,
                                               uint* __restrict__ H,
                                               uchar* __restrict__ wclass,
                                               int E, int NB, int NBLK) {
    __shared__ uint hist[512];
    int blk = blockIdx.x, t = threadIdx.x;
    hist[t] = 0; hist[t + 256] = 0;
    __syncthreads();
    int lo = blk * PART_R, hi = min(lo + PART_R, E);
    for (int i = lo + t; i < hi; i += 256) {
        wclass[i] = 0;
        atomicAdd(&hist[((uint)ei[E + i]) >> 8], 1u);
    }
    __syncthreads();
    for (int b = t; b < NB; b += 256) H[(size_t)b * NBLK + blk] = hist[b];
}

// ---- exclusive scan (2 kernels)
__global__ void scan_partial_kernel(const int* __restrict__ cnt, int* __restrict__ startv,
                                    int* __restrict__ bsum, int n) {
    __shared__ int s[256];
    int t = threadIdx.x;
    int base = blockIdx.x * SCAN_CH + t * 4;
    int v0 = (base + 0 < n) ? cnt[base + 0] : 0;
    int v1 = (base + 1 < n) ? cnt[base + 1] : 0;
    int v2 = (base + 2 < n) ? cnt[base + 2] : 0;
    int v3 = (base + 3 < n) ? cnt[base + 3] : 0;
    int loc = v0 + v1 + v2 + v3;
    s[t] = loc;
    __syncthreads();
    for (int off = 1; off < 256; off <<= 1) {
        int u = (t >= off) ? s[t - off] : 0;
        __syncthreads();
        s[t] += u;
        __syncthreads();
    }
    int ex = s[t] - loc;
    if (t == 255) bsum[blockIdx.x] = s[255];   // raw block sum
    if (base + 0 < n) startv[base + 0] = ex;
    if (base + 1 < n) startv[base + 1] = ex + v0;
    if (base + 2 < n) startv[base + 2] = ex + v0 + v1;
    if (base + 3 < n) startv[base + 3] = ex + v0 + v1 + v2;
}

// scan_add with inline bsum prefix: block covers 256 indices, i/SCAN_CH constant per block.
__global__ void scan_add_kernel(int* __restrict__ startv, const int* __restrict__ bsum, int n) {
    __shared__ int soff;
    int b = blockIdx.x;
    if (threadIdx.x == 0) {
        int q = (b * 256) / SCAN_CH;
        int acc = 0;
        for (int j = 0; j < q; ++j) acc += bsum[j];
        soff = acc;
    }
    __syncthreads();
    int i = b * 256 + threadIdx.x;
    if (i < n) startv[i] += soff;
}

// K3: LDS-staged partition to BUCKET granularity.
// Pack rec = row<<10 | (col&255)<<2 | wclass; write bucket-grouped.
__global__ __launch_bounds__(256) void k3_partition(
        const int* __restrict__ ei, const uchar* __restrict__ wclass,
        const uint* __restrict__ Hs, uint* __restrict__ recSorted,
        int E, int NB, int NBLK) {
    __shared__ uint recs[PART_R];
    __shared__ ushort sbkt[PART_R];
    __shared__ uint hist[512];
    __shared__ uint scanA[512];
    __shared__ uint scanB[512];
    __shared__ int  gbase[512];
    __shared__ uint cursor[512];
    int blk = blockIdx.x, t = threadIdx.x;
    int lo = blk * PART_R, hi = min(lo + PART_R, E);
    int cntTot = hi - lo;
    hist[t] = 0; hist[t + 256] = 0;
    __syncthreads();
    for (int i = lo + t; i < hi; i += 256)
        atomicAdd(&hist[((uint)ei[E + i]) >> 8], 1u);
    __syncthreads();
    uint* src = scanA; uint* dst = scanB;
    src[t] = hist[t]; src[t + 256] = hist[t + 256];
    __syncthreads();
    for (int off = 1; off < 512; off <<= 1) {
        dst[t]       = src[t]       + ((t >= off)       ? src[t - off]       : 0u);
        dst[t + 256] = src[t + 256] + ((t + 256 >= off) ? src[t + 256 - off] : 0u);
        __syncthreads();
        uint* tmp = src; src = dst; dst = tmp;
    }
    uint l0 = (t == 0) ? 0u : src[t - 1];
    uint l1 = src[t + 255];
    cursor[t] = l0; cursor[t + 256] = l1;
    if (t < NB)       gbase[t]       = (int)Hs[(size_t)t * NBLK + blk]         - (int)l0;
    if (t + 256 < NB) gbase[t + 256] = (int)Hs[(size_t)(t + 256) * NBLK + blk] - (int)l1;
    __syncthreads();
    for (int i = lo + t; i < hi; i += 256) {
        uint row = (uint)ei[i];
        uint col = (uint)ei[E + i];
        uint b = col >> 8;
        uint rec = (row << 10) | ((col & 255u) << 2) | (uint)wclass[i];
        uint slot = atomicAdd(&cursor[b], 1u);
        recs[slot] = rec;
        sbkt[slot] = (ushort)b;
    }
    __syncthreads();
    for (int s = t; s < cntTot; s += 256)
        recSorted[gbase[sbkt[s]] + s] = recs[s];
}

// K2: per-bucket node stats: cnt, startv (node-exact global CSR offset), dis = rsqrt(deg+1)
__global__ __launch_bounds__(256) void k2_stats(
        const uint* __restrict__ recSorted, const uint* __restrict__ Hs,
        const uint* __restrict__ spq,
        uint* __restrict__ cnt, uint* __restrict__ startv, float* __restrict__ dis,
        int E, int NB, int NBLK, int n_nodes) {
    __shared__ uint hcnt[256], hdeg[256], sA[256], sB[256];
    __shared__ uint sq[4];
    int b = blockIdx.x, t = threadIdx.x;
    hcnt[t] = 0; hdeg[t] = 0;
    if (t < 4) sq[t] = spq[t];
    __syncthreads();
    uint lo = Hs[(size_t)b * NBLK];
    uint hi = (b + 1 < NB) ? Hs[(size_t)(b + 1) * NBLK] : (uint)E;
    for (uint i = lo + t; i < hi; i += 256) {
        uint r = recSorted[i];
        atomicAdd(&hcnt[(r >> 2) & 255u], 1u);
        atomicAdd(&hdeg[(r >> 2) & 255u], sq[r & 3u]);
    }
    __syncthreads();
    uint* src = sA; uint* dst = sB;
    src[t] = hcnt[t];
    __syncthreads();
    for (int off = 1; off < 256; off <<= 1) {
        dst[t] = src[t] + ((t >= off) ? src[t - off] : 0u);
        __syncthreads();
        uint* tmp = src; src = dst; dst = tmp;
    }
    uint excl = (t == 0) ? 0u : src[t - 1];
    int node = (b << 8) + t;
    if (node < n_nodes) {
        cnt[node] = hcnt[t];
        startv[node] = lo + excl;
        float deg = (float)hdeg[t] * (1.0f / DEG_SCALE) + 1.0f;
        dis[node] = rsqrtf(deg);
    }
}

// K4: second-level partition + payload fill. payload = row<<15 | round(norm*32768)
__global__ __launch_bounds__(256) void k4_payload(
        const uint* __restrict__ recSorted, const uint* __restrict__ Hs,
        const float* __restrict__ sp, const float* __restrict__ dis,
        const uint* __restrict__ startv,
        uint* __restrict__ payload, int E, int NB, int NBLK, int n_nodes) {
    __shared__ float disl[256];
    __shared__ uint cur[256];
    __shared__ float spl[4];
    int b = blockIdx.x, t = threadIdx.x;
    int node = (b << 8) + t;
    disl[t] = (node < n_nodes) ? dis[node] : 0.0f;
    cur[t]  = (node < n_nodes) ? startv[node] : 0u;
    if (t < 4) spl[t] = sp[t];
    __syncthreads();
    uint lo = Hs[(size_t)b * NBLK];
    uint hi = (b + 1 < NB) ? Hs[(size_t)(b + 1) * NBLK] : (uint)E;
    for (uint i = lo + t; i < hi; i += 256) {
        uint r = recSorted[i];
        uint row = r >> 10;
        uint c = (r >> 2) & 255u;
        float nrm = dis[row] * spl[r & 3u] * disl[c];
        uint pos = atomicAdd(&cur[c], 1u);
        payload[pos] = (row << 15) | __float2uint_rn(nrm * NRM_SCALE);
    }
}

// h2 = x @ W_eff + b_eff, stored fp16 (stride-64 padded, zeros at d>=61).
// First blocks also zero-init pooled (runs before gather).
__global__ void h2_kernel(const float* __restrict__ x, const float* __restrict__ W_eff,
                          const float* __restrict__ b_eff,
                          __half* __restrict__ h2, float* __restrict__ pooled, int g64,
                          int n_nodes) {
    int gid = blockIdx.x * 256 + threadIdx.x;
    if (gid < g64) pooled[gid] = 0.0f;
    int node = blockIdx.x * 4 + (threadIdx.x >> 6);
    int d = threadIdx.x & 63;
    if (node >= n_nodes) return;
    float v = 0.f;
    if (d < HGCN) {
        v = b_eff[d];
#pragma unroll
        for (int f = 0; f < F_IN; ++f)
            v += x[node * F_IN + f] * W_eff[f * 64 + d];
    }
    h2[node * 64 + d] = __float2half(v);
}

// gather + gelu + pool, fused. 2 edges/wave in parallel (group g = lane>>5, edge 2k+g);
// lane owns a dim PAIR via one half2 load. Unroll 8 -> 8 h2-line loads in flight per group.
__global__ void gather_pool_kernel(const uint* __restrict__ payload,
                                   const uint* __restrict__ startv, const uint* __restrict__ cnt,
                                   const float* __restrict__ dis,
                                   const __half2* __restrict__ h2v,
                                   const float* __restrict__ b_gcn, const int* __restrict__ batch,
                                   float* __restrict__ pooled, int n_nodes) {
    int node = blockIdx.x * 4 + (threadIdx.x >> 6);
    int lane = threadIdx.x & 63;
    int g = lane >> 5;          // edge-parity group
    int sub = lane & 31;        // dim pair index (dims 2*sub, 2*sub+1)
    if (node >= n_nodes) return;
    int s = (int)startv[node];
    int m = (int)cnt[node];
    const float inv = 1.0f / NRM_SCALE;
    float accx = 0.f, accy = 0.f;
    if (g == 0) {               // self-loop term only in group 0 (avoid double count)
        float di = dis[node];
        float2 hv = __half22float2(h2v[node * 32 + sub]);
        accx = di * di * hv.x;
        accy = di * di * hv.y;
    }
    for (int j0 = 0; j0 < m; j0 += 64) {
        uint p = 0;
        if (j0 + lane < m) p = payload[s + j0 + lane];  // coalesced 256B chunk load
        int lim = min(64, m - j0);
        int npairs = (lim + 1) >> 1;
        int k = 0;
        for (; k + 8 <= npairs; k += 8) {               // 8 loads in flight per group
            uint p0 = __shfl(p, 2 * (k + 0) + g);
            uint p1 = __shfl(p, 2 * (k + 1) + g);
            uint p2 = __shfl(p, 2 * (k + 2) + g);
            uint p3 = __shfl(p, 2 * (k + 3) + g);
            uint p4 = __shfl(p, 2 * (k + 4) + g);
            uint p5 = __shfl(p, 2 * (k + 5) + g);
            uint p6 = __shfl(p, 2 * (k + 6) + g);
            uint p7 = __shfl(p, 2 * (k + 7) + g);
            float2 h0 = __half22float2(h2v[(p0 >> 15) * 32 + sub]);
            float2 h1 = __half22float2(h2v[(p1 >> 15) * 32 + sub]);
            float2 h2f = __half22float2(h2v[(p2 >> 15) * 32 + sub]);
            float2 h3 = __half22float2(h2v[(p3 >> 15) * 32 + sub]);
            float2 h4 = __half22float2(h2v[(p4 >> 15) * 32 + sub]);
            float2 h5 = __half22float2(h2v[(p5 >> 15) * 32 + sub]);
            float2 h6 = __half22float2(h2v[(p6 >> 15) * 32 + sub]);
            float2 h7 = __half22float2(h2v[(p7 >> 15) * 32 + sub]);
            float w0 = (float)(p0 & 32767u) * inv;
            float w1 = (float)(p1 & 32767u) * inv;
            float w2 = (float)(p2 & 32767u) * inv;
            float w3 = (float)(p3 & 32767u) * inv;
            float w4 = (float)(p4 & 32767u) * inv;
            float w5 = (float)(p5 & 32767u) * inv;
            float w6 = (float)(p6 & 32767u) * inv;
            float w7 = (float)(p7 & 32767u) * inv;
            accx += w0 * h0.x; accy += w0 * h0.y;
            accx += w1 * h1.x; accy += w1 * h1.y;
            accx += w2 * h2f.x; accy += w2 * h2f.y;
            accx += w3 * h3.x; accy += w3 * h3.y;
            accx += w4 * h4.x; accy += w4 * h4.y;
            accx += w5 * h5.x; accy += w5 * h5.y;
            accx += w6 * h6.x; accy += w6 * h6.y;
            accx += w7 * h7.x; accy += w7 * h7.y;
        }
        for (; k < npairs; ++k) {
            uint pk = __shfl(p, 2 * k + g);
            float2 hk = __half22float2(h2v[(pk >> 15) * 32 + sub]);
            float wk = (float)(pk & 32767u) * inv;
            accx += wk * hk.x; accy += wk * hk.y;
        }
    }
    // combine the two edge-parity groups
    accx += __shfl_xor(accx, 32);
    accy += __shfl_xor(accy, 32);
    // epilogue: group 0 writes even dim, group 1 writes odd dim
    int d = 2 * sub + g;
    float val = g ? accy : accx;
    if (d < HGCN) {
        float v = gelu_exact(val + b_gcn[d]);
        atomic_add_f32(&pooled[batch[node] * 64 + d], v);
    }
}

// per-graph head
__global__ void final_kernel(const float* __restrict__ pooled,
                             const float* __restrict__ fn_avg,
                             const float* __restrict__ inf_rate,
                             const float* __restrict__ W_fn1, const float* __restrict__ b_fn1,
                             const float* __restrict__ W_fn2, const float* __restrict__ b_fn2,
                             const float* __restrict__ W_bb1, const float* __restrict__ b_bb1,
                             const float* __restrict__ W_out, const float* __restrict__ b_out,
                             float* __restrict__ logits) {
    __shared__ float z[64];
    __shared__ float t1[16];
    int g = blockIdx.x;
    int t = threadIdx.x;
    if (t < HGCN) z[t] = pooled[g * 64 + t];
    float e0 = fn_avg[g * 2], e1 = fn_avg[g * 2 + 1], e2 = inf_rate[g];
    if (t < 16) {
        float a = e0 * W_fn1[t] + e1 * W_fn1[16 + t] + e2 * W_fn1[32 + t] + b_fn1[t];
        t1[t] = gelu_exact(a);
    }
    __syncthreads();
    if (t < 3) {
        float a = b_fn2[t];
#pragma unroll
        for (int k = 0; k < 16; ++k) a += t1[k] * W_fn2[k * 3 + t];
        z[HGCN + t] = a;
    }
    __syncthreads();
    float acc = b_bb1[t];
#pragma unroll 8
    for (int k = 0; k < 64; ++k) acc += z[k] * W_bb1[k * 64 + t];
    float p = gelu_exact(acc) * W_out[t];
#pragma unroll
    for (int off = 32; off > 0; off >>= 1) p += __shfl_down(p, off);
    if (t == 0) logits[g] = p + b_out[0];
}

extern "C" void kernel_launch(void* const* d_in, const int* in_sizes, int n_in,
                              void* d_out, int out_size, void* d_ws, size_t ws_size,
                              hipStream_t stream) {
    const float* x        = (const float*)d_in[0];
    const int*   ei       = (const int*)d_in[1];
    const int*   batch    = (const int*)d_in[2];
    const int*   known    = (const int*)d_in[3];
    const int*   unk      = (const int*)d_in[4];
    const int*   obs      = (const int*)d_in[5];
    const float* fn_avg   = (const float*)d_in[6];
    const float* inf_rate = (const float*)d_in[7];
    const float* msg_w    = (const float*)d_in[8];
    const float* W_emb    = (const float*)d_in[9];
    const float* b_emb    = (const float*)d_in[10];
    const float* W_gcn    = (const float*)d_in[11];
    const float* b_gcn    = (const float*)d_in[12];
    const float* W_fn1    = (const float*)d_in[13];
    const float* b_fn1    = (const float*)d_in[14];
    const float* W_fn2    = (const float*)d_in[15];
    const float* b_fn2    = (const float*)d_in[16];
    const float* W_bb1    = (const float*)d_in[17];
    const float* b_bb1    = (const float*)d_in[18];
    const float* W_out    = (const float*)d_in[19];
    const float* b_out    = (const float*)d_in[20];
    float* logits = (float*)d_out;

    const int n_nodes = in_sizes[0] / F_IN;
    const int E       = in_sizes[1] / 2;
    const int nk = in_sizes[3], nu = in_sizes[4], no = in_sizes[5];
    const int G = in_sizes[6] / 2;

    const int NB   = (n_nodes + 255) >> 8;
    const int NBLK = (E + PART_R - 1) / PART_R;
    const int L    = NB * NBLK;
    const int nbL  = (L + SCAN_CH - 1) / SCAN_CH;

    char* ws = (char*)d_ws;
    size_t off = 0;
    auto alloc = [&](size_t bytes) -> void* {
        void* p = ws + off;
        off += (bytes + 255) & ~size_t(255);
        return p;
    };
    uchar*  wclass    = (uchar*)alloc(sizeof(uchar) * (size_t)E);
    uint*   recSorted = (uint*)alloc(sizeof(uint) * (size_t)E);
    uint*   H         = (uint*)alloc(sizeof(uint) * (size_t)L);
    uint*   Hs        = (uint*)alloc(sizeof(uint) * (size_t)L);
    int*    bsum      = (int*)alloc(sizeof(int) * (size_t)(nbL + 1));
    __half* h2        = (__half*)alloc(sizeof(__half) * (size_t)n_nodes * 64);
    uint*   payload   = (uint*)alloc(sizeof(uint) * (size_t)E);
    uint*   cntv      = (uint*)alloc(sizeof(uint) * (size_t)n_nodes);
    uint*   startv    = (uint*)alloc(sizeof(uint) * (size_t)n_nodes);
    float*  dis       = (float*)alloc(sizeof(float) * (size_t)n_nodes);
    float*  pooled    = (float*)alloc(sizeof(float) * (size_t)G * 64);
    float*  W_eff     = (float*)alloc(sizeof(float) * F_IN * 64);
    float*  b_eff     = (float*)alloc(sizeof(float) * 64);
    float*  sp        = (float*)alloc(sizeof(float) * 4);
    uint*   spq       = (uint*)alloc(sizeof(uint) * 4);

    prep_kernel<<<1, 64, 0, stream>>>(msg_w, W_emb, b_emb, W_gcn, sp, spq, W_eff, b_eff);
    k1_hist<<<NBLK, 256, 0, stream>>>(ei, H, wclass, E, NB, NBLK);   // also zeroes wclass
    set_mask_u8<<<(nk + 255) / 256, 256, 0, stream>>>(wclass, known, 1, nk);
    set_mask_u8<<<(nu + 255) / 256, 256, 0, stream>>>(wclass, unk, 2, nu);
    set_mask_u8<<<(no + 255) / 256, 256, 0, stream>>>(wclass, obs, 3, no);
    scan_partial_kernel<<<nbL, 256, 0, stream>>>((const int*)H, (int*)Hs, bsum, L);
    scan_add_kernel<<<(L + 255) / 256, 256, 0, stream>>>((int*)Hs, bsum, L);
    k3_partition<<<NBLK, 256, 0, stream>>>(ei, wclass, Hs, recSorted, E, NB, NBLK);
    k2_stats<<<NB, 256, 0, stream>>>(recSorted, Hs, spq, cntv, startv, dis, E, NB, NBLK, n_nodes);
    h2_kernel<<<(n_nodes + 3) / 4, 256, 0, stream>>>(x, W_eff, b_eff, h2, pooled, G * 64, n_nodes);
    k4_payload<<<NB, 256, 0, stream>>>(recSorted, Hs, sp, dis, startv, payload, E, NB, NBLK, n_nodes);
    gather_pool_kernel<<<(n_nodes + 3) / 4, 256, 0, stream>>>(payload, startv, cntv, dis,
                                                              (const __half2*)h2, b_gcn, batch,
                                                              pooled, n_nodes);
    final_kernel<<<G, 64, 0, stream>>>(pooled, fn_avg, inf_rate, W_fn1, b_fn1,
                                       W_fn2, b_fn2, W_bb1, b_bb1, W_out, b_out, logits);
}